// Round 5
// baseline (1089.337 us; speedup 1.0000x reference)
//
#include <hip/hip_runtime.h>
#include <hip/hip_bf16.h>

typedef __attribute__((ext_vector_type(8))) short short8;
typedef __attribute__((ext_vector_type(16))) float floatx16;

constexpr int MM = 65536;   // batch
constexpr int KK = 512;     // inner dim
constexpr int NN = 512;     // out dim per layer

#define GM 128
#define GN 128
#define GK 32
#define LDT 40   // LDS row stride in bf16: row base bank = 20*r mod 32 -> good rotation

// round-to-nearest-even fp32 -> bf16 (bit-level, finite inputs)
__device__ __forceinline__ unsigned short bf16_rn(float v) {
  unsigned u = __float_as_uint(v);
  return (unsigned short)((u + 0x7FFFu + ((u >> 16) & 1u)) >> 16);
}
__device__ __forceinline__ float bf16_to_f32(unsigned short h) {
  return __uint_as_float((unsigned)h << 16);
}

// src fp32 -> (hi, lo) bf16 arrays. n4 = element count / 4.
__global__ __launch_bounds__(256) void split_kernel(
    const float* __restrict__ src, unsigned short* __restrict__ h,
    unsigned short* __restrict__ l, int n4) {
  int i = blockIdx.x * 256 + threadIdx.x;
  if (i >= n4) return;
  float4 v = ((const float4*)src)[i];
  ushort4 hv, lv;
  hv.x = bf16_rn(v.x); lv.x = bf16_rn(v.x - bf16_to_f32(hv.x));
  hv.y = bf16_rn(v.y); lv.y = bf16_rn(v.y - bf16_to_f32(hv.y));
  hv.z = bf16_rn(v.z); lv.z = bf16_rn(v.z - bf16_to_f32(hv.z));
  hv.w = bf16_rn(v.w); lv.w = bf16_rn(v.w - bf16_to_f32(hv.w));
  ((ushort4*)h)[i] = hv;
  ((ushort4*)l)[i] = lv;
}

// C[M,N] = act(A @ W^T + bias) via 3-term split-bf16 MFMA:
// A ~ Ah+Al, W ~ Wh+Wl (bf16); C ~ Ah*Wh + Ah*Wl + Al*Wh (Al*Wl ~ 2^-18, dropped).
// R3-verified: ~170 us/GEMM, zero argmax flips, absmax 9.8e-4.
template<bool RELU, bool SPLIT>
__global__ __launch_bounds__(256, 2) void gemm_mfma(
    const unsigned short* __restrict__ Ah, const unsigned short* __restrict__ Al,
    const unsigned short* __restrict__ Wh, const unsigned short* __restrict__ Wl,
    const float* __restrict__ bias,
    unsigned short* __restrict__ Ch, unsigned short* __restrict__ Cl,
    float* __restrict__ Cf) {
  __shared__ unsigned short sAh[GM][LDT], sAl[GM][LDT];
  __shared__ unsigned short sBh[GN][LDT], sBl[GN][LDT];
  const int tid = threadIdx.x;
  const int lane = tid & 63;
  const int wid = tid >> 6;
  const int wr = wid >> 1;         // wave row (0..1)
  const int wc = wid & 1;          // wave col (0..1)
  const int bm = blockIdx.x, bn = blockIdx.y;
  const size_t Abase = (size_t)bm * GM * KK;
  const size_t Bbase = (size_t)bn * GN * KK;

  floatx16 acc[2][2];
#pragma unroll
  for (int i = 0; i < 2; ++i)
#pragma unroll
    for (int j = 0; j < 2; ++j)
#pragma unroll
      for (int r = 0; r < 16; ++r) acc[i][j][r] = 0.f;

  for (int k0 = 0; k0 < KK; k0 += GK) {
#pragma unroll
    for (int t = 0; t < 2; ++t) {
      int s = tid + t * 256;
      int row = s >> 2;            // 0..127
      int cc = (s & 3) * 8;        // 0,8,16,24
      size_t goff = (size_t)row * KK + k0 + cc;
      *(short8*)&sAh[row][cc] = *(const short8*)(Ah + Abase + goff);
      *(short8*)&sAl[row][cc] = *(const short8*)(Al + Abase + goff);
      *(short8*)&sBh[row][cc] = *(const short8*)(Wh + Bbase + goff);
      *(short8*)&sBl[row][cc] = *(const short8*)(Wl + Bbase + goff);
    }
    __syncthreads();

#pragma unroll
    for (int ks = 0; ks < 2; ++ks) {
      const int ko = ks * 16 + (lane >> 5) * 8;
      short8 fah[2], fal[2], fbh[2], fbl[2];
#pragma unroll
      for (int ri = 0; ri < 2; ++ri) {
        int row = wr * 64 + ri * 32 + (lane & 31);
        fah[ri] = *(const short8*)&sAh[row][ko];
        fal[ri] = *(const short8*)&sAl[row][ko];
      }
#pragma unroll
      for (int si = 0; si < 2; ++si) {
        int col = wc * 64 + si * 32 + (lane & 31);
        fbh[si] = *(const short8*)&sBh[col][ko];
        fbl[si] = *(const short8*)&sBl[col][ko];
      }
#pragma unroll
      for (int ri = 0; ri < 2; ++ri)
#pragma unroll
        for (int si = 0; si < 2; ++si) {
          acc[ri][si] = __builtin_amdgcn_mfma_f32_32x32x16_bf16(fah[ri], fbh[si], acc[ri][si], 0, 0, 0);
          acc[ri][si] = __builtin_amdgcn_mfma_f32_32x32x16_bf16(fah[ri], fbl[si], acc[ri][si], 0, 0, 0);
          acc[ri][si] = __builtin_amdgcn_mfma_f32_32x32x16_bf16(fal[ri], fbh[si], acc[ri][si], 0, 0, 0);
        }
    }
    __syncthreads();
  }

#pragma unroll
  for (int si = 0; si < 2; ++si) {
    int col = bn * GN + wc * 64 + si * 32 + (lane & 31);
    float bv = bias[col];
#pragma unroll
    for (int ri = 0; ri < 2; ++ri) {
#pragma unroll
      for (int r = 0; r < 16; ++r) {
        int row = bm * GM + wr * 64 + ri * 32 + (r & 3) + 8 * (r >> 2) + 4 * (lane >> 5);
        float v = acc[ri][si][r] + bv;
        if (RELU) v = fmaxf(v, 0.f);
        size_t idx = (size_t)row * NN + col;
        if (SPLIT) {
          unsigned short h = bf16_rn(v);
          Ch[idx] = h;
          Cl[idx] = bf16_rn(v - bf16_to_f32(h));
        } else {
          Cf[idx] = v;
        }
      }
    }
  }
}

// Per 16 batch rows: logits = m @ Wc^T + bc ; y = argmax(logits) (softmax is
// monotonic, probs unused) ; z[e] = m . Wg[y, e, :] + bg[y, e] for e<16.
// R4: Wc read from global (32 KB, L1/L2-hot; LDS 67.5->34 KB, 2->4 blocks/CU)
// and 8 independent accumulators per dot (dep chain 128 -> 16 steps).
__global__ __launch_bounds__(256) void head_kernel(
    const float* __restrict__ m2, const float* __restrict__ Wc,
    const float* __restrict__ bc, const float* __restrict__ Wg,
    const float* __restrict__ bg, float* __restrict__ z_out,
    float* __restrict__ y_out) {
  __shared__ float sm[16][516];   // stride 516: float4-aligned, banks 4r+4k -> conflict-free
  __shared__ float slog[16][17];
  __shared__ int sy[16];
  const int tid = threadIdx.x;
  const int r = tid >> 4;    // row within block
  const int c = tid & 15;    // class / latent index
  const size_t row0 = (size_t)blockIdx.x * 16;

  // stage 16 m-rows (32 KB): 2048 float4, 8 per thread, fully coalesced
#pragma unroll
  for (int t = 0; t < 8; ++t) {
    int s = tid + t * 256;         // 0..2047
    int rr = s >> 7;               // 0..15
    int kc = (s & 127) << 2;       // 0..508
    *(float4*)&sm[rr][kc] = *(const float4*)(m2 + (row0 + rr) * 512 + kc);
  }
  __syncthreads();

  {
    const float4* wc = (const float4*)(Wc + (size_t)c * 512);
    float acc[8];
#pragma unroll
    for (int u = 0; u < 8; ++u) acc[u] = 0.f;
#pragma unroll 2
    for (int k4 = 0; k4 < 128; k4 += 8) {
#pragma unroll
      for (int u = 0; u < 8; ++u) {
        float4 a = *(const float4*)&sm[r][(k4 + u) * 4];
        float4 w = wc[k4 + u];
        acc[u] += a.x * w.x + a.y * w.y + a.z * w.z + a.w * w.w;
      }
    }
    float dot = ((acc[0] + acc[1]) + (acc[2] + acc[3])) +
                ((acc[4] + acc[5]) + (acc[6] + acc[7]));
    slog[r][c] = dot + bc[c];
  }
  __syncthreads();

  if (c == 0) {
    // strict > keeps first max: matches np/jnp argmax tie-breaking
    float best = slog[r][0];
    int bi = 0;
#pragma unroll
    for (int j = 1; j < 16; ++j) {
      float v = slog[r][j];
      if (v > best) { best = v; bi = j; }
    }
    sy[r] = bi;
    y_out[row0 + r] = (float)bi;
  }
  __syncthreads();

  {
    const int y = sy[r];
    const float4* wg = (const float4*)(Wg + ((size_t)y * 32 + c) * 512);  // Wg[y, c, :]
    float acc[8];
#pragma unroll
    for (int u = 0; u < 8; ++u) acc[u] = 0.f;
#pragma unroll 2
    for (int k4 = 0; k4 < 128; k4 += 8) {
#pragma unroll
      for (int u = 0; u < 8; ++u) {
        float4 a = *(const float4*)&sm[r][(k4 + u) * 4];
        float4 w = wg[k4 + u];
        acc[u] += a.x * w.x + a.y * w.y + a.z * w.z + a.w * w.w;
      }
    }
    float zacc = ((acc[0] + acc[1]) + (acc[2] + acc[3])) +
                 ((acc[4] + acc[5]) + (acc[6] + acc[7]));
    z_out[(row0 + r) * 16 + c] = zacc + bg[y * 32 + c];
  }
}

extern "C" void kernel_launch(void* const* d_in, const int* in_sizes, int n_in,
                              void* d_out, int out_size, void* d_ws, size_t ws_size,
                              hipStream_t stream) {
  const float* x  = (const float*)d_in[0];
  const float* W0 = (const float*)d_in[1];
  const float* b0 = (const float*)d_in[2];
  const float* W1 = (const float*)d_in[3];
  const float* b1 = (const float*)d_in[4];
  const float* W2 = (const float*)d_in[5];
  const float* b2 = (const float*)d_in[6];
  const float* Wc = (const float*)d_in[7];
  const float* bc = (const float*)d_in[8];
  const float* Wg = (const float*)d_in[9];
  const float* bg = (const float*)d_in[10];

  const size_t NEL = (size_t)MM * KK;         // 33.5M elements
  unsigned short* Ah = (unsigned short*)d_ws;           // 64 MiB
  unsigned short* Al = Ah + NEL;                        // 64 MiB
  unsigned short* Bh = Al + NEL;                        // 64 MiB
  unsigned short* Bl = Bh + NEL;                        // 64 MiB
  float* m3 = (float*)Bh;                               // GEMM3 out reuses bufB as fp32 (128 MiB)

  // W splits staged in d_out (3 MiB < 4.25 MiB); head fully overwrites d_out last.
  unsigned short* w0h = (unsigned short*)d_out;
  unsigned short* w0l = w0h + 262144;
  unsigned short* w1h = w0l + 262144;
  unsigned short* w1l = w1h + 262144;
  unsigned short* w2h = w1l + 262144;
  unsigned short* w2l = w2h + 262144;

  float* z_out = (float*)d_out;
  float* y_out = z_out + (size_t)MM * 16;

  split_kernel<<<(int)(NEL / 4 / 256), 256, 0, stream>>>(x, Ah, Al, (int)(NEL / 4));
  split_kernel<<<256, 256, 0, stream>>>(W0, w0h, w0l, 65536);
  split_kernel<<<256, 256, 0, stream>>>(W1, w1h, w1l, 65536);
  split_kernel<<<256, 256, 0, stream>>>(W2, w2h, w2l, 65536);

  dim3 grid(MM / GM, NN / GN);
  gemm_mfma<true , true ><<<grid, 256, 0, stream>>>(Ah, Al, w0h, w0l, b0, Bh, Bl, nullptr);
  gemm_mfma<true , true ><<<grid, 256, 0, stream>>>(Bh, Bl, w1h, w1l, b1, Ah, Al, nullptr);
  gemm_mfma<false, false><<<grid, 256, 0, stream>>>(Ah, Al, w2h, w2l, b2, nullptr, nullptr, m3);
  head_kernel<<<MM / 16, 256, 0, stream>>>(m3, Wc, bc, Wg, bg, z_out, y_out);
}

// Round 6
// 697.976 us; speedup vs baseline: 1.5607x; 1.5607x over previous
//
#include <hip/hip_runtime.h>
#include <hip/hip_bf16.h>

typedef __attribute__((ext_vector_type(8))) short short8;
typedef __attribute__((ext_vector_type(16))) float floatx16;
typedef __attribute__((ext_vector_type(4))) float floatx4;

constexpr int MM = 65536;   // batch
constexpr int KK = 512;     // inner dim
constexpr int NN = 512;     // out dim per layer

#define GM 128
#define GN 128
#define GK 32
#define LDT 40   // LDS row stride (shorts): frag-read bank pattern 4*((5r+q)&7) is uniform-8 = b128 floor

// round-to-nearest-even fp32 -> bf16 (bit-level, finite inputs)
__device__ __forceinline__ unsigned short bf16_rn(float v) {
  unsigned u = __float_as_uint(v);
  return (unsigned short)((u + 0x7FFFu + ((u >> 16) & 1u)) >> 16);
}
__device__ __forceinline__ float bf16_to_f32(unsigned short h) {
  return __uint_as_float((unsigned)h << 16);
}

// src fp32 -> (hi, lo) bf16 arrays. n4 = element count / 4.
__global__ __launch_bounds__(256) void split_kernel(
    const float* __restrict__ src, unsigned short* __restrict__ h,
    unsigned short* __restrict__ l, int n4) {
  int i = blockIdx.x * 256 + threadIdx.x;
  if (i >= n4) return;
  float4 v = ((const float4*)src)[i];
  ushort4 hv, lv;
  hv.x = bf16_rn(v.x); lv.x = bf16_rn(v.x - bf16_to_f32(hv.x));
  hv.y = bf16_rn(v.y); lv.y = bf16_rn(v.y - bf16_to_f32(hv.y));
  hv.z = bf16_rn(v.z); lv.z = bf16_rn(v.z - bf16_to_f32(hv.z));
  hv.w = bf16_rn(v.w); lv.w = bf16_rn(v.w - bf16_to_f32(hv.w));
  ((ushort4*)h)[i] = hv;
  ((ushort4*)l)[i] = lv;
}

// C[M,N] = act(A @ W^T + bias) via 3-term split-bf16 MFMA (R3-verified).
template<bool RELU, bool SPLIT>
__global__ __launch_bounds__(256, 2) void gemm_mfma(
    const unsigned short* __restrict__ Ah, const unsigned short* __restrict__ Al,
    const unsigned short* __restrict__ Wh, const unsigned short* __restrict__ Wl,
    const float* __restrict__ bias,
    unsigned short* __restrict__ Ch, unsigned short* __restrict__ Cl,
    float* __restrict__ Cf) {
  __shared__ unsigned short sAh[GM][LDT], sAl[GM][LDT];
  __shared__ unsigned short sBh[GN][LDT], sBl[GN][LDT];
  const int tid = threadIdx.x;
  const int lane = tid & 63;
  const int wid = tid >> 6;
  const int wr = wid >> 1;
  const int wc = wid & 1;
  const int bm = blockIdx.x, bn = blockIdx.y;
  const size_t Abase = (size_t)bm * GM * KK;
  const size_t Bbase = (size_t)bn * GN * KK;

  floatx16 acc[2][2];
#pragma unroll
  for (int i = 0; i < 2; ++i)
#pragma unroll
    for (int j = 0; j < 2; ++j)
#pragma unroll
      for (int r = 0; r < 16; ++r) acc[i][j][r] = 0.f;

  for (int k0 = 0; k0 < KK; k0 += GK) {
#pragma unroll
    for (int t = 0; t < 2; ++t) {
      int s = tid + t * 256;
      int row = s >> 2;
      int cc = (s & 3) * 8;
      size_t goff = (size_t)row * KK + k0 + cc;
      *(short8*)&sAh[row][cc] = *(const short8*)(Ah + Abase + goff);
      *(short8*)&sAl[row][cc] = *(const short8*)(Al + Abase + goff);
      *(short8*)&sBh[row][cc] = *(const short8*)(Wh + Bbase + goff);
      *(short8*)&sBl[row][cc] = *(const short8*)(Wl + Bbase + goff);
    }
    __syncthreads();

#pragma unroll
    for (int ks = 0; ks < 2; ++ks) {
      const int ko = ks * 16 + (lane >> 5) * 8;
      short8 fah[2], fal[2], fbh[2], fbl[2];
#pragma unroll
      for (int ri = 0; ri < 2; ++ri) {
        int row = wr * 64 + ri * 32 + (lane & 31);
        fah[ri] = *(const short8*)&sAh[row][ko];
        fal[ri] = *(const short8*)&sAl[row][ko];
      }
#pragma unroll
      for (int si = 0; si < 2; ++si) {
        int col = wc * 64 + si * 32 + (lane & 31);
        fbh[si] = *(const short8*)&sBh[col][ko];
        fbl[si] = *(const short8*)&sBl[col][ko];
      }
#pragma unroll
      for (int ri = 0; ri < 2; ++ri)
#pragma unroll
        for (int si = 0; si < 2; ++si) {
          acc[ri][si] = __builtin_amdgcn_mfma_f32_32x32x16_bf16(fah[ri], fbh[si], acc[ri][si], 0, 0, 0);
          acc[ri][si] = __builtin_amdgcn_mfma_f32_32x32x16_bf16(fah[ri], fbl[si], acc[ri][si], 0, 0, 0);
          acc[ri][si] = __builtin_amdgcn_mfma_f32_32x32x16_bf16(fal[ri], fbh[si], acc[ri][si], 0, 0, 0);
        }
    }
    __syncthreads();
  }

#pragma unroll
  for (int si = 0; si < 2; ++si) {
    int col = bn * GN + wc * 64 + si * 32 + (lane & 31);
    float bv = bias[col];
#pragma unroll
    for (int ri = 0; ri < 2; ++ri) {
#pragma unroll
      for (int r = 0; r < 16; ++r) {
        int row = bm * GM + wr * 64 + ri * 32 + (r & 3) + 8 * (r >> 2) + 4 * (lane >> 5);
        float v = acc[ri][si][r] + bv;
        if (RELU) v = fmaxf(v, 0.f);
        size_t idx = (size_t)row * NN + col;
        if (SPLIT) {
          unsigned short h = bf16_rn(v);
          Ch[idx] = h;
          Cl[idx] = bf16_rn(v - bf16_to_f32(h));
        } else {
          Cf[idx] = v;
        }
      }
    }
  }
}

// H2: mu_all[65536,256] = mh @ wgh^T + wgb (1-term bf16 MFMA; z tolerance is lenient).
__global__ __launch_bounds__(256, 2) void gemm_mu(
    const unsigned short* __restrict__ Ahm, const unsigned short* __restrict__ Wh,
    const float* __restrict__ bias, float* __restrict__ Cf) {
  __shared__ unsigned short sAh[GM][LDT];
  __shared__ unsigned short sBh[GN][LDT];
  const int tid = threadIdx.x;
  const int lane = tid & 63;
  const int wid = tid >> 6;
  const int wr = wid >> 1;
  const int wc = wid & 1;
  const int bm = blockIdx.x, bn = blockIdx.y;
  const size_t Abase = (size_t)bm * GM * KK;
  const size_t Bbase = (size_t)bn * GN * KK;

  floatx16 acc[2][2];
#pragma unroll
  for (int i = 0; i < 2; ++i)
#pragma unroll
    for (int j = 0; j < 2; ++j)
#pragma unroll
      for (int r = 0; r < 16; ++r) acc[i][j][r] = 0.f;

  for (int k0 = 0; k0 < KK; k0 += GK) {
#pragma unroll
    for (int t = 0; t < 2; ++t) {
      int s = tid + t * 256;
      int row = s >> 2;
      int cc = (s & 3) * 8;
      size_t goff = (size_t)row * KK + k0 + cc;
      *(short8*)&sAh[row][cc] = *(const short8*)(Ahm + Abase + goff);
      *(short8*)&sBh[row][cc] = *(const short8*)(Wh + Bbase + goff);
    }
    __syncthreads();
#pragma unroll
    for (int ks = 0; ks < 2; ++ks) {
      const int ko = ks * 16 + (lane >> 5) * 8;
      short8 fa[2], fb[2];
#pragma unroll
      for (int ri = 0; ri < 2; ++ri)
        fa[ri] = *(const short8*)&sAh[wr * 64 + ri * 32 + (lane & 31)][ko];
#pragma unroll
      for (int si = 0; si < 2; ++si)
        fb[si] = *(const short8*)&sBh[wc * 64 + si * 32 + (lane & 31)][ko];
#pragma unroll
      for (int ri = 0; ri < 2; ++ri)
#pragma unroll
        for (int si = 0; si < 2; ++si)
          acc[ri][si] = __builtin_amdgcn_mfma_f32_32x32x16_bf16(fa[ri], fb[si], acc[ri][si], 0, 0, 0);
    }
    __syncthreads();
  }

#pragma unroll
  for (int si = 0; si < 2; ++si) {
    int col = bn * GN + wc * 64 + si * 32 + (lane & 31);
    float bv = bias[col];
#pragma unroll
    for (int ri = 0; ri < 2; ++ri)
#pragma unroll
      for (int r = 0; r < 16; ++r) {
        int row = bm * GM + wr * 64 + ri * 32 + (r & 3) + 8 * (r >> 2) + 4 * (lane >> 5);
        Cf[(size_t)row * 256 + col] = acc[ri][si][r] + bv;
      }
  }
}

// H1: logits[65536,16] = (mh+ml) @ (wch+wcl)^T + bc via 3-term 16x16x32 MFMA,
// then per-row argmax -> y. A: row=lane&15, k=(lane>>4)*8+j; B symmetric;
// C/D: col=lane&15, row=(lane>>4)*4+reg  [m89/m91 verified].
__global__ __launch_bounds__(256) void logits_kernel(
    const unsigned short* __restrict__ mh, const unsigned short* __restrict__ ml,
    const unsigned short* __restrict__ wch, const unsigned short* __restrict__ wcl,
    const float* __restrict__ bc, float* __restrict__ y_out) {
  __shared__ unsigned short smh[64][LDT], sml[64][LDT];
  __shared__ float slog[64][17];
  const int tid = threadIdx.x;
  const int lane = tid & 63;
  const int wid = tid >> 6;            // wave -> rows wid*16..+16
  const size_t row0 = (size_t)blockIdx.x * 64;
  const int fr = lane & 15;
  const int fq = lane >> 4;

  floatx4 acc = {0.f, 0.f, 0.f, 0.f};
  const unsigned short* bh = wch + fr * 512 + fq * 8;   // Wc-split: 32 KB, L1/L2-hot
  const unsigned short* bl = wcl + fr * 512 + fq * 8;

  for (int k0 = 0; k0 < 512; k0 += 32) {
    {
      int row = tid >> 2, cc = (tid & 3) * 8;          // 256 chunks = 64 rows x 4
      size_t g = (row0 + row) * 512 + k0 + cc;
      *(short8*)&smh[row][cc] = *(const short8*)(mh + g);
      *(short8*)&sml[row][cc] = *(const short8*)(ml + g);
    }
    __syncthreads();
    short8 ah = *(const short8*)&smh[wid * 16 + fr][fq * 8];
    short8 al = *(const short8*)&sml[wid * 16 + fr][fq * 8];
    short8 fbh = *(const short8*)(bh + k0);
    short8 fbl = *(const short8*)(bl + k0);
    acc = __builtin_amdgcn_mfma_f32_16x16x32_bf16(ah, fbh, acc, 0, 0, 0);
    acc = __builtin_amdgcn_mfma_f32_16x16x32_bf16(ah, fbl, acc, 0, 0, 0);
    acc = __builtin_amdgcn_mfma_f32_16x16x32_bf16(al, fbh, acc, 0, 0, 0);
    __syncthreads();
  }
#pragma unroll
  for (int r = 0; r < 4; ++r)
    slog[wid * 16 + fq * 4 + r][fr] = acc[r] + bc[fr];
  __syncthreads();
  if (tid < 64) {
    float best = slog[tid][0];
    int bi = 0;
#pragma unroll
    for (int j = 1; j < 16; ++j) {     // strict >: first-max, matches np argmax
      float v = slog[tid][j];
      if (v > best) { best = v; bi = j; }
    }
    y_out[row0 + tid] = (float)bi;
  }
}

// prep: Wg[16,32,512] mu-rows -> wgh[256,512] bf16; wgb[col]=bg[col/16,col%16]
__global__ __launch_bounds__(256) void prep_wg(
    const float* __restrict__ Wg, const float* __restrict__ bg,
    unsigned short* __restrict__ wgh, float* __restrict__ wgb) {
  int gid = blockIdx.x * 256 + threadIdx.x;    // 32768 threads x 4 elems
  if (gid >= 32768) return;
  int r = gid >> 7;
  int c4 = (gid & 127) * 4;
  int k = r >> 4, e = r & 15;
  float4 v = *(const float4*)(Wg + ((size_t)k * 32 + e) * 512 + c4);
  ushort4 h;
  h.x = bf16_rn(v.x); h.y = bf16_rn(v.y); h.z = bf16_rn(v.z); h.w = bf16_rn(v.w);
  *(ushort4*)(wgh + (size_t)r * 512 + c4) = h;
  if (c4 == 0) wgb[r] = bg[k * 32 + e];
}

// H3: z[b,e] = mu_all[b, y_b*16 + e]  (bias already folded into mu_all)
__global__ __launch_bounds__(256) void select_kernel(
    const float* __restrict__ mu, const float* __restrict__ y_in,
    float* __restrict__ z_out) {
  int gid = blockIdx.x * 256 + threadIdx.x;    // 1048576
  int b = gid >> 4, e = gid & 15;
  int y = (int)y_in[b];
  z_out[gid] = mu[(size_t)b * 256 + y * 16 + e];
}

extern "C" void kernel_launch(void* const* d_in, const int* in_sizes, int n_in,
                              void* d_out, int out_size, void* d_ws, size_t ws_size,
                              hipStream_t stream) {
  const float* x  = (const float*)d_in[0];
  const float* W0 = (const float*)d_in[1];
  const float* b0 = (const float*)d_in[2];
  const float* W1 = (const float*)d_in[3];
  const float* b1 = (const float*)d_in[4];
  const float* W2 = (const float*)d_in[5];
  const float* b2 = (const float*)d_in[6];
  const float* Wc = (const float*)d_in[7];
  const float* bc = (const float*)d_in[8];
  const float* Wg = (const float*)d_in[9];
  const float* bg = (const float*)d_in[10];

  const size_t NEL = (size_t)MM * KK;
  unsigned short* Ah = (unsigned short*)d_ws;           // 64 MiB each
  unsigned short* Al = Ah + NEL;
  unsigned short* Bh = Al + NEL;
  unsigned short* Bl = Bh + NEL;
  // After GEMM3 (out: Bh/Bl = m-split), Ah/Al regions are free:
  float* mu_all = (float*)Ah;                           // 65536*256*4 = 64 MiB exactly
  unsigned short* wch = Al;                             // 16 KB
  unsigned short* wcl = Al + 8192;                      // 16 KB
  unsigned short* wgh = Al + 16384;                     // 256 KB
  float* wgb = (float*)(Al + 16384 + 131072);           // 1 KB

  // W-layer splits staged in d_out (3 MiB < 4.5 MiB); overwritten only by final z.
  unsigned short* w0h = (unsigned short*)d_out;
  unsigned short* w0l = w0h + 262144;
  unsigned short* w1h = w0l + 262144;
  unsigned short* w1l = w1h + 262144;
  unsigned short* w2h = w1l + 262144;
  unsigned short* w2l = w2h + 262144;

  float* z_out = (float*)d_out;
  float* y_out = z_out + (size_t)MM * 16;               // at +4 MiB, clear of w-splits

  split_kernel<<<(int)(NEL / 4 / 256), 256, 0, stream>>>(x, Ah, Al, (int)(NEL / 4));
  split_kernel<<<256, 256, 0, stream>>>(W0, w0h, w0l, 65536);
  split_kernel<<<256, 256, 0, stream>>>(W1, w1h, w1l, 65536);
  split_kernel<<<256, 256, 0, stream>>>(W2, w2h, w2l, 65536);

  dim3 grid(MM / GM, NN / GN);
  gemm_mfma<true , true ><<<grid, 256, 0, stream>>>(Ah, Al, w0h, w0l, b0, Bh, Bl, nullptr);
  gemm_mfma<true , true ><<<grid, 256, 0, stream>>>(Bh, Bl, w1h, w1l, b1, Ah, Al, nullptr);
  gemm_mfma<false, true ><<<grid, 256, 0, stream>>>(Ah, Al, w2h, w2l, b2, Bh, Bl, nullptr);

  // head preps (Ah/Al free from here)
  split_kernel<<<8, 256, 0, stream>>>(Wc, wch, wcl, 2048);
  prep_wg<<<128, 256, 0, stream>>>(Wg, bg, wgh, wgb);

  logits_kernel<<<MM / 64, 256, 0, stream>>>(Bh, Bl, wch, wcl, bc, y_out);
  gemm_mu<<<dim3(MM / GM, 2), 256, 0, stream>>>(Bh, wgh, wgb, mu_all);
  select_kernel<<<MM * 16 / 256, 256, 0, stream>>>(mu_all, y_out, z_out);
}